// Round 3
// baseline (59126.276 us; speedup 1.0000x reference)
//
#include <hip/hip_runtime.h>
#include <hip/hip_cooperative_groups.h>
#include <cstdio>

namespace cg = cooperative_groups;

// ---------------- dims ----------------
static constexpr int cB = 32, cTENC = 256, cENCD = 512, cTDEC = 500, cMEL = 80,
    cNSTEP = 250, cPRE = 256, cAD = 128, cAR = 1024, cDR = 1024, cFLT = 32,
    cKSZ = 31, cPADC = 15, cNG = 4096;
static constexpr int cKA = cPRE + cENCD + cAR;   // 1792 : [x | ctx | h_a]
static constexpr int cKD = cAR + cENCD + cDR;    // 2560 : [h_a | ctx | dec_h]
static constexpr int cKM = cDR + cENCD;          // 1536 : [dec_h | ctx]
static constexpr int cNMP = 192;                 // padded 161 (160 mel + 1 stop)
static constexpr int cNSA = 14;                  // attn k-splits (span 128)
static constexpr int cNSD = 16;                  // dec  k-splits (span 160)

typedef unsigned short ushortT;
typedef unsigned int uintT;

// ---------------- output layout (floats) ----------------
static constexpr size_t MEL_OFF = 0;
static constexpr size_t STOP_OFF = (size_t)cB * cTDEC * cMEL;      // 1,280,000
static constexpr size_t ATT_OFF = STOP_OFF + (size_t)cB * cTDEC;   // 1,296,000

// ---------------- workspace layout (float units) ----------------
// WATB/WDTB are bf16 (ushort) arrays occupying half the float count.
static constexpr size_t WS_WATB = 0;                                   // us[1792][4096]
static constexpr size_t WS_WDTB = WS_WATB + (size_t)cKA * cNG / 2;     // us[2560][4096]
static constexpr size_t WS_WMT  = WS_WDTB + (size_t)cKD * cNG / 2;     // f[1536][192]
static constexpr size_t WS_WQT  = WS_WMT  + (size_t)cKM * cNMP;        // f[1024][128]
static constexpr size_t WS_WMTR = WS_WQT  + (size_t)cAR * cAD;         // f[512][128]
static constexpr size_t WS_PM   = WS_WMTR + (size_t)cENCD * cAD;       // f[32][256][128]
static constexpr size_t WS_XPRE = WS_PM   + (size_t)cB * cTENC * cAD;  // f[250][256][32]
static constexpr size_t WS_XA   = WS_XPRE + (size_t)cNSTEP * cPRE * cB;// f[2][1792][32]
static constexpr size_t WS_XD   = WS_XA   + (size_t)2 * cKA * cB;      // f[2560][32]
static constexpr size_t WS_CA   = WS_XD   + (size_t)cKD * cB;          // f[32][1024]
static constexpr size_t WS_CD   = WS_CA   + (size_t)cB * cAR;          // f[32][1024]
static constexpr size_t WS_CUM  = WS_CD   + (size_t)cB * cDR;          // f[32][256]
static constexpr size_t WS_GA   = WS_CUM  + (size_t)cB * cTENC;        // f[32][14][4096]
static constexpr size_t WS_GD   = WS_GA   + (size_t)cB * cNSA * cNG;   // f[32][16][4096]
static constexpr size_t WS_PROJ = WS_GD   + (size_t)cB * cNSD * cNG;   // f[250][1536][32]
static constexpr size_t WS_TOTAL = WS_PROJ + (size_t)cNSTEP * cKM * cB;
// X1 (prenet intermediate) aliases GA/GD region: used only pre-loop.
static constexpr size_t WS_X1   = WS_GA;                               // f[250][32][256]

struct Args {
  const float *enc, *inputs;
  const int *mlen;
  const float *W1, *b1, *W2, *b2, *Wm;
  const float *Wih_a, *Whh_a, *bih_a, *bhh_a;
  const float *Wq, *conv_w, *conv_b, *WL, *v;
  const float *Wih_d, *Whh_d, *bih_d, *bhh_d;
  const float *Wmel, *bmel, *Wstop, *bstop;
  float *out;
  float *ws;
};

union SharedU {
  float xs[(160 + 8) * 32];              // gemv x-slice stage (+PF over-read pad)
  struct {
    float h[cAR];                        // attn LSTM hidden (this step)
    float pq[cAD];
    float cumext[cTENC + 2 * cPADC];     // cum with conv halo
    float eparts[2][cTENC];
    float e[cTENC];
    float sred[16];
    float loc[cFLT * 257];               // conv output, padded stride
    float wl[cAD * 33];                  // WL padded
    float cw[cFLT * cKSZ];
    float vv[cAD];
  } attn;                                // ~63 KB
  float melred[cB][164];
};

__device__ __forceinline__ float sigm_f(float x) { return 1.f / (1.f + __expf(-x)); }
__device__ __forceinline__ float tanh_f(float x) {
  float e = __expf(2.f * x);
  return 1.f - 2.f / (e + 1.f);
}

// Batch-32 GEMV partial, bf16 weights, register-prefetch pipelined.
// WG covers 512 cols (block cb) x KSPAN k-rows -> part[b][slot][col].
// Thread tile: 8 consecutive cols (one uint4 = 8 bf16) x 4 batches.
// x (fp32) staged in LDS, one broadcast b128 read / k.
template <int KSPAN, int NS>
static __device__ void gemv_bf16(const ushortT* __restrict__ WT,
                                 const float* __restrict__ xT,
                                 float* __restrict__ part,
                                 int cb, int k0, int slot, float* __restrict__ xs) {
  const int tid = threadIdx.x;
  {
    const float4* src = (const float4*)(xT + (size_t)k0 * cB);
    float4* dst = (float4*)xs;
    for (int i = tid; i < KSPAN * 8; i += 512) dst[i] = src[i];
  }
  __syncthreads();
  const int cq = tid & 63, bq = tid >> 6;           // 64 col-groups x 8 batch-groups
  const int col0 = cb * 512 + cq * 8;
  const ushortT* wp = WT + (size_t)k0 * cNG + col0;
  const float4* xp = (const float4*)xs + bq;        // stride 8 float4 per k
  float acc[8][4];
#pragma unroll
  for (int c = 0; c < 8; ++c)
#pragma unroll
    for (int j = 0; j < 4; ++j) acc[c][j] = 0.f;

  constexpr int PF = 8;                             // prefetch depth
  uint4 wbuf[PF];
  float4 xbuf[PF];
#pragma unroll
  for (int i = 0; i < PF; ++i) {
    wbuf[i] = *(const uint4*)(wp + (size_t)i * cNG);
    xbuf[i] = xp[(size_t)i * 8];
  }
  for (int kb = 0; kb < KSPAN; kb += PF) {
#pragma unroll
    for (int i = 0; i < PF; ++i) {
      const uint4 w = wbuf[i];
      const float4 x4 = xbuf[i];
      const size_t kn = (size_t)(kb + i + PF);
      // prefetch next block (over-reads past KSPAN are into adjacent ws / LDS pad)
      wbuf[i] = *(const uint4*)(wp + kn * cNG);
      xbuf[i] = xp[kn * 8];
      float wf[8];
      wf[0] = __uint_as_float(w.x << 16);
      wf[1] = __uint_as_float(w.x & 0xFFFF0000u);
      wf[2] = __uint_as_float(w.y << 16);
      wf[3] = __uint_as_float(w.y & 0xFFFF0000u);
      wf[4] = __uint_as_float(w.z << 16);
      wf[5] = __uint_as_float(w.z & 0xFFFF0000u);
      wf[6] = __uint_as_float(w.w << 16);
      wf[7] = __uint_as_float(w.w & 0xFFFF0000u);
      const float xv[4] = {x4.x, x4.y, x4.z, x4.w};
#pragma unroll
      for (int c = 0; c < 8; ++c)
#pragma unroll
        for (int j = 0; j < 4; ++j) acc[c][j] = fmaf(wf[c], xv[j], acc[c][j]);
    }
  }
  const int b0 = bq * 4;
#pragma unroll
  for (int j = 0; j < 4; ++j) {
    float* dst = &part[(((size_t)(b0 + j)) * NS + slot) * cNG + col0];
    float4 o0, o1;
    o0.x = acc[0][j]; o0.y = acc[1][j]; o0.z = acc[2][j]; o0.w = acc[3][j];
    o1.x = acc[4][j]; o1.y = acc[5][j]; o1.z = acc[6][j]; o1.w = acc[7][j];
    *(float4*)dst = o0;
    *(float4*)(dst + 4) = o1;
  }
}

// Decoder LSTM cell for batch b, step s: reduce cNSD gd partials, apply cell,
// write dec_h into XD rows [1536,2560) and PROJ[s] rows [0,1024).
static __device__ void dec_cell(const Args& a, float* ws, int b, int s) {
  const int tid = threadIdx.x;
  const float* gd = ws + WS_GD + (size_t)b * cNSD * cNG;
  for (int h = tid; h < cDR; h += 512) {
    float g4[4];
#pragma unroll
    for (int gi = 0; gi < 4; ++gi) {
      const int n = gi * cDR + h;
      float sm = a.bih_d[n] + a.bhh_d[n];
#pragma unroll
      for (int p = 0; p < cNSD; ++p) sm += gd[(size_t)p * cNG + n];
      g4[gi] = sm;
    }
    const float co = ws[WS_CD + (size_t)b * cDR + h];
    const float cn = sigm_f(g4[1]) * co + sigm_f(g4[0]) * tanh_f(g4[2]);
    const float hn = sigm_f(g4[3]) * tanh_f(cn);
    ws[WS_CD + (size_t)b * cDR + h] = cn;
    ws[WS_XD + (size_t)(cAR + cENCD + h) * cB + b] = hn;
    ws[WS_PROJ + ((size_t)s * cKM + h) * cB + b] = hn;
  }
}

// Attention workgroup for batch b at step t.
static __device__ void attn_wg(const Args& a, float* ws, int b, int t,
                               float* __restrict__ xa2, SharedU& sh) {
  const int tid = threadIdx.x;
  const float* ga = ws + WS_GA + (size_t)b * cNSA * cNG;
  // 1. reduce ga partials + attn LSTM cell
  for (int h = tid; h < cAR; h += 512) {
    float g4[4];
#pragma unroll
    for (int gi = 0; gi < 4; ++gi) {
      const int n = gi * cAR + h;
      float s = a.bih_a[n] + a.bhh_a[n];
#pragma unroll
      for (int p = 0; p < cNSA; ++p) s += ga[(size_t)p * cNG + n];
      g4[gi] = s;
    }
    const float co = ws[WS_CA + (size_t)b * cAR + h];
    const float cn = sigm_f(g4[1]) * co + sigm_f(g4[0]) * tanh_f(g4[2]);
    const float hn = sigm_f(g4[3]) * tanh_f(cn);
    ws[WS_CA + (size_t)b * cAR + h] = cn;
    sh.attn.h[h] = hn;
    xa2[(size_t)(cPRE + cENCD + h) * cB + b] = hn;   // next step attn-gates input
    ws[WS_XD + (size_t)h * cB + b] = hn;             // dec-gates input (this step)
  }
  __syncthreads();
  // 2. pq partials (reuse loc as [4][128] scratch) + small LDS loads
  {
    const int d = tid & 127, kc = tid >> 7;
    float acc = 0.f;
    const float* wq = ws + WS_WQT;
    const int k0 = kc * 256;
    for (int k = k0; k < k0 + 256; ++k) acc = fmaf(sh.attn.h[k], wq[(size_t)k * cAD + d], acc);
    sh.attn.loc[kc * 128 + d] = acc;
  }
  for (int i = tid; i < cAD * 33; i += 512) {
    const int dd = i / 33, f = i - dd * 33;
    sh.attn.wl[i] = (f < cFLT) ? a.WL[dd * cFLT + f] : 0.f;
  }
  for (int i = tid; i < cFLT * cKSZ; i += 512) sh.attn.cw[i] = a.conv_w[i];
  if (tid < cAD) sh.attn.vv[tid] = a.v[tid];
  if (tid < cTENC) sh.attn.cumext[cPADC + tid] = ws[WS_CUM + (size_t)b * cTENC + tid];
  if (tid < 2 * cPADC) sh.attn.cumext[tid < cPADC ? tid : cTENC + tid] = 0.f;
  __syncthreads();
  if (tid < cAD)
    sh.attn.pq[tid] = sh.attn.loc[tid] + sh.attn.loc[128 + tid] +
                      sh.attn.loc[256 + tid] + sh.attn.loc[384 + tid];
  __syncthreads();
  // 3. conv31 over cum
  for (int i = tid; i < cFLT * cTENC; i += 512) {
    const int f = i >> 8, te = i & 255;
    float s = a.conv_b[f];
#pragma unroll
    for (int j = 0; j < cKSZ; ++j) s = fmaf(sh.attn.cumext[te + j], sh.attn.cw[f * cKSZ + j], s);
    sh.attn.loc[f * 257 + te] = s;
  }
  __syncthreads();
  // 4. energies
  {
    const int d = tid & 127, tq = tid >> 7, wv = tid >> 6;
    float wlr[cFLT];
#pragma unroll
    for (int f = 0; f < cFLT; ++f) wlr[f] = sh.attn.wl[d * 33 + f];
    const float pqd = sh.attn.pq[d], vd = sh.attn.vv[d];
    const float* pmb = ws + WS_PM + (size_t)b * cTENC * cAD;
    for (int tt = 0; tt < cTENC / 4; ++tt) {
      const int te = tt * 4 + tq;
      float s = pqd + pmb[(size_t)te * cAD + d];
#pragma unroll
      for (int f = 0; f < cFLT; ++f) s = fmaf(sh.attn.loc[f * 257 + te], wlr[f], s);
      float p = tanh_f(s) * vd;
#pragma unroll
      for (int off = 32; off > 0; off >>= 1) p += __shfl_xor(p, off, 64);
      if ((tid & 63) == 0) sh.attn.eparts[wv & 1][te] = p;
    }
  }
  __syncthreads();
  // 5. mask + softmax over 256
  const int mlen = a.mlen[b];
  if (tid < cTENC) {
    float ev = sh.attn.eparts[0][tid] + sh.attn.eparts[1][tid];
    if (tid >= mlen) ev = -1e9f;
    sh.attn.e[tid] = ev;
  }
  __syncthreads();
  const int wv = tid >> 6;
  {
    float xv = sh.attn.e[tid & 255];
#pragma unroll
    for (int off = 32; off > 0; off >>= 1) xv = fmaxf(xv, __shfl_xor(xv, off, 64));
    if ((tid & 63) == 0) sh.attn.sred[wv] = xv;
  }
  __syncthreads();
  float m = sh.attn.sred[0];
#pragma unroll
  for (int i = 1; i < 8; ++i) m = fmaxf(m, sh.attn.sred[i]);
  const float pex = (tid < cTENC) ? __expf(sh.attn.e[tid] - m) : 0.f;
  {
    float sv = pex;
#pragma unroll
    for (int off = 32; off > 0; off >>= 1) sv += __shfl_xor(sv, off, 64);
    if ((tid & 63) == 0) sh.attn.sred[8 + wv] = sv;
  }
  __syncthreads();
  float ssum = 0.f;
#pragma unroll
  for (int i = 0; i < 8; ++i) ssum += sh.attn.sred[8 + i];
  const float rs = 1.f / ssum;
  if (tid < cTENC) {
    const float al = pex * rs;
    sh.attn.e[tid] = al;
    a.out[ATT_OFF + ((size_t)b * cNSTEP + t) * cTENC + tid] = al;
    ws[WS_CUM + (size_t)b * cTENC + tid] += al;
  }
  __syncthreads();
  // 6. ctx = align @ encoder_outputs[b]
  {
    const int k = tid;   // 512 = ENCD
    float acc = 0.f;
    const float* encb = a.enc + (size_t)b * cTENC * cENCD + k;
    for (int te = 0; te < cTENC; ++te) acc = fmaf(sh.attn.e[te], encb[(size_t)te * cENCD], acc);
    xa2[(size_t)(cPRE + k) * cB + b] = acc;                       // next attn-gates
    ws[WS_XD + (size_t)(cAR + k) * cB + b] = acc;                 // dec-gates
    ws[WS_PROJ + ((size_t)t * cKM + cDR + k) * cB + b] = acc;     // projection input
  }
}

// Post-loop batched mel/stop projection over all steps.
static __device__ void mel_proj(const Args& a, float* ws, SharedU& sh) {
  const int tid = threadIdx.x;
  const int c = tid & 255, sub = tid >> 8;   // two 768-row K halves
  for (int t = blockIdx.x; t < cNSTEP; t += gridDim.x) {
    float acc[cB];
#pragma unroll
    for (int b = 0; b < cB; ++b) acc[b] = 0.f;
    if (c < 161) {
      const float* wmt = ws + WS_WMT;
      const float* xr0 = ws + WS_PROJ + (size_t)t * cKM * cB;
      const int k0 = sub * 768;
      for (int k = k0; k < k0 + 768; ++k) {
        const float w = wmt[(size_t)k * cNMP + c];
        const float* xr = xr0 + (size_t)k * cB;
#pragma unroll
        for (int b = 0; b < cB; ++b) acc[b] = fmaf(w, xr[b], acc[b]);
      }
    }
    __syncthreads();
    if (sub == 1 && c < 161) {
#pragma unroll
      for (int b = 0; b < cB; ++b) sh.melred[b][c] = acc[b];
    }
    __syncthreads();
    if (sub == 0 && c < 161) {
      if (c < 160) {
        const int fr = c / 80, mm = c % 80;
        const float bm = a.bmel[c];
#pragma unroll
        for (int b = 0; b < cB; ++b) {
          const float val = acc[b] + sh.melred[b][c] + bm;
          a.out[MEL_OFF + ((size_t)b * cTDEC + (2 * t + fr)) * cMEL + mm] = val;
        }
      } else {
        const float bs = a.bstop[0];
#pragma unroll
        for (int b = 0; b < cB; ++b) {
          const float sp = sigm_f(acc[b] + sh.melred[b][c] + bs);
          a.out[STOP_OFF + (size_t)b * cTDEC + 2 * t] = sp;
          a.out[STOP_OFF + (size_t)b * cTDEC + 2 * t + 1] = sp;
        }
      }
    }
    __syncthreads();
  }
}

// ---------------- setup kernels ----------------
__device__ __forceinline__ ushortT f2b(float f) {
  const uintT u = __float_as_uint(f);
  return (ushortT)((u + 0x7FFFu + ((u >> 16) & 1u)) >> 16);   // RNE
}

// Tiled transpose: src[N][K] fp32 -> dst[k][n] fp32, dst row pitch dpitch.
__global__ void k_transpose(const float* __restrict__ src, float* __restrict__ dst,
                            int N, int K, int dpitch) {
  __shared__ float tile[64][65];
  const int tkn = K >> 6;
  const int tk = blockIdx.x % tkn, tn = blockIdx.x / tkn;
  const int c = threadIdx.x & 63, r4 = threadIdx.x >> 6;   // 256 threads
  const int n0 = tn << 6, k0 = tk << 6;
#pragma unroll
  for (int rr = 0; rr < 16; ++rr) {
    const int r = r4 * 16 + rr;
    tile[r][c] = src[(size_t)(n0 + r) * K + k0 + c];
  }
  __syncthreads();
#pragma unroll
  for (int rr = 0; rr < 16; ++rr) {
    const int r = r4 * 16 + rr;
    dst[(size_t)(k0 + r) * dpitch + n0 + c] = tile[c][r];
  }
}

// Tiled transpose with bf16 output: src[N][K] fp32 -> dst[k][n] bf16.
__global__ void k_transpose_b16(const float* __restrict__ src, ushortT* __restrict__ dst,
                                int N, int K, int dpitch) {
  __shared__ float tile[64][65];
  const int tkn = K >> 6;
  const int tk = blockIdx.x % tkn, tn = blockIdx.x / tkn;
  const int c = threadIdx.x & 63, r4 = threadIdx.x >> 6;   // 256 threads
  const int n0 = tn << 6, k0 = tk << 6;
#pragma unroll
  for (int rr = 0; rr < 16; ++rr) {
    const int r = r4 * 16 + rr;
    tile[r][c] = src[(size_t)(n0 + r) * K + k0 + c];
  }
  __syncthreads();
#pragma unroll
  for (int rr = 0; rr < 16; ++rr) {
    const int r = r4 * 16 + rr;
    dst[(size_t)(k0 + r) * dpitch + n0 + c] = f2b(tile[c][r]);
  }
}

__global__ void k_prep_small(Args a) {
  // WMT: [1536][192] fp32 from Wmel [160][1536] + Wstop [1536]
  const size_t i = (size_t)blockIdx.x * blockDim.x + threadIdx.x;
  if (i >= (size_t)cKM * cNMP) return;
  const int k = (int)(i / cNMP), c = (int)(i % cNMP);
  a.ws[WS_WMT + i] = (c < 160) ? a.Wmel[(size_t)c * cKM + k]
                               : (c == 160 ? a.Wstop[k] : 0.f);
}

__global__ void k_prenet1(Args a) {
  const size_t i = (size_t)blockIdx.x * blockDim.x + threadIdx.x;
  if (i >= (size_t)cNSTEP * cB * cPRE) return;
  const int j = i & 255, b = (i >> 8) & 31, n = (int)(i >> 13);
  float acc = a.b1[j];
  if (n > 0) {
    const float* fr = a.inputs + ((size_t)b * cTDEC + (2 * n - 1)) * cMEL;
    for (int k = 0; k < cMEL; ++k) acc = fmaf(fr[k], a.W1[j * cMEL + k], acc);
  }
  a.ws[WS_X1 + i] = fmaxf(acc, 0.f);
}

__global__ void k_prenet2(Args a) {
  const size_t i = (size_t)blockIdx.x * blockDim.x + threadIdx.x;
  if (i >= (size_t)cNSTEP * cPRE * cB) return;
  const int b = i & 31, j = (i >> 5) & 255, n = (int)(i >> 13);
  float acc = a.b2[j];
  const float* x1 = a.ws + WS_X1 + ((size_t)n * cB + b) * cPRE;
  for (int k = 0; k < cPRE; ++k) acc = fmaf(x1[k], a.W2[j * cPRE + k], acc);
  a.ws[WS_XPRE + i] = fmaxf(acc, 0.f);   // layout [n][j][b]
}

__global__ void k_pm(Args a) {
  const size_t i = (size_t)blockIdx.x * blockDim.x + threadIdx.x;
  if (i >= (size_t)cB * cTENC * cAD) return;
  const int d = i & 127, tt = (i >> 7) & 255, b = (int)(i >> 15);
  float acc = 0.f;
  const float* er = a.enc + ((size_t)b * cTENC + tt) * cENCD;
  const float* wt = a.ws + WS_WMTR;
  for (int k = 0; k < cENCD; ++k) acc = fmaf(er[k], wt[(size_t)k * cAD + d], acc);
  a.ws[WS_PM + i] = acc;
}

__global__ void k_init(Args a) {
  const size_t ztot = (size_t)2 * cKA * cB + (size_t)cKD * cB + (size_t)cB * cAR +
                      (size_t)cB * cDR + (size_t)cB * cTENC;   // XA..CUM contiguous
  const size_t i = (size_t)blockIdx.x * blockDim.x + threadIdx.x;
  if (i < ztot) a.ws[WS_XA + i] = 0.f;
  if (i < (size_t)cPRE * cB) a.ws[WS_XA + i] = a.ws[WS_XPRE + i];  // x_0 into XA[0]
}

// ---------------- persistent cooperative loop ----------------
// Pipeline: PhaseA(t) = attn-gates GEMV(t) || dec-gates GEMV(t-1)
//           PhaseB(t) = attention(t)+ctx(t) || dec_cell(t-1) || x-copy(t+1)
__global__ void __launch_bounds__(512, 1) k_loop(Args a) {
  cg::grid_group grid = cg::this_grid();
  __shared__ SharedU sh;
  float* ws = a.ws;
  const ushortT* watb = (const ushortT*)(ws + WS_WATB);
  const ushortT* wdtb = (const ushortT*)(ws + WS_WDTB);
  const int wg = blockIdx.x;
  const int tid = threadIdx.x;

  for (int t = 0; t <= cNSTEP; ++t) {
    const float* xa = ws + WS_XA + (size_t)(t & 1) * cKA * cB;
    float* xa2 = ws + WS_XA + (size_t)((t + 1) & 1) * cKA * cB;
    // ---- Phase A ----
    if (wg < 112) {
      if (t < cNSTEP) {
        const int s = wg >> 3, cb = wg & 7;
        gemv_bf16<128, cNSA>(watb, xa, ws + WS_GA, cb, s * 128, s, sh.xs);
      }
    } else if (wg < 240) {
      if (t >= 1) {
        const int i = wg - 112, s = i >> 3, cb = i & 7;
        gemv_bf16<160, cNSD>(wdtb, ws + WS_XD, ws + WS_GD, cb, s * 160, s, sh.xs);
      }
    }
    grid.sync();
    // ---- Phase B ----
    if (wg < 32) {
      if (t < cNSTEP) attn_wg(a, ws, wg, t, xa2, sh);
    } else if (wg < 64) {
      if (t >= 1) dec_cell(a, ws, wg - 32, t - 1);
    } else if (wg < 80) {
      if (t + 1 < cNSTEP) {
        const int i = (wg - 64) * 512 + tid;   // 16*512 = 8192 = PRE*B exactly
        xa2[i] = ws[WS_XPRE + (size_t)(t + 1) * cPRE * cB + i];
      }
    }
    grid.sync();
  }
  mel_proj(a, ws, sh);
}

// ---------------- host ----------------
extern "C" void kernel_launch(void* const* d_in, const int* in_sizes, int n_in,
                              void* d_out, int out_size, void* d_ws, size_t ws_size,
                              hipStream_t stream) {
  (void)in_sizes; (void)n_in; (void)out_size;
  Args a;
  a.enc = (const float*)d_in[0];
  a.inputs = (const float*)d_in[1];
  a.mlen = (const int*)d_in[2];
  a.W1 = (const float*)d_in[3];  a.b1 = (const float*)d_in[4];
  a.W2 = (const float*)d_in[5];  a.b2 = (const float*)d_in[6];
  a.Wm = (const float*)d_in[7];
  a.Wih_a = (const float*)d_in[8];  a.Whh_a = (const float*)d_in[9];
  a.bih_a = (const float*)d_in[10]; a.bhh_a = (const float*)d_in[11];
  a.Wq = (const float*)d_in[12];
  a.conv_w = (const float*)d_in[13]; a.conv_b = (const float*)d_in[14];
  a.WL = (const float*)d_in[15];     a.v = (const float*)d_in[16];
  a.Wih_d = (const float*)d_in[17];  a.Whh_d = (const float*)d_in[18];
  a.bih_d = (const float*)d_in[19];  a.bhh_d = (const float*)d_in[20];
  a.Wmel = (const float*)d_in[21];   a.bmel = (const float*)d_in[22];
  a.Wstop = (const float*)d_in[23];  a.bstop = (const float*)d_in[24];
  a.out = (float*)d_out;
  a.ws = (float*)d_ws;

  if (ws_size < WS_TOTAL * sizeof(float)) {
    fprintf(stderr, "kernel_launch: ws too small: need %zu bytes, have %zu\n",
            WS_TOTAL * sizeof(float), ws_size);
    return;
  }

  float* ws = a.ws;
  ushortT* watb = (ushortT*)(ws + WS_WATB);
  ushortT* wdtb = (ushortT*)(ws + WS_WDTB);
  // Big weight transposes -> bf16, K-major:
  // Wih_a [4096][768] -> WATB rows [0,768)
  k_transpose_b16<<<dim3((768 / 64) * (4096 / 64)), dim3(256), 0, stream>>>(
      a.Wih_a, watb, 4096, 768, cNG);
  // Whh_a [4096][1024] -> WATB rows [768,1792)
  k_transpose_b16<<<dim3((1024 / 64) * (4096 / 64)), dim3(256), 0, stream>>>(
      a.Whh_a, watb + (size_t)768 * cNG, 4096, 1024, cNG);
  // Wih_d [4096][1536] -> WDTB rows [0,1536)
  k_transpose_b16<<<dim3((1536 / 64) * (4096 / 64)), dim3(256), 0, stream>>>(
      a.Wih_d, wdtb, 4096, 1536, cNG);
  // Whh_d [4096][1024] -> WDTB rows [1536,2560)
  k_transpose_b16<<<dim3((1024 / 64) * (4096 / 64)), dim3(256), 0, stream>>>(
      a.Whh_d, wdtb + (size_t)1536 * cNG, 4096, 1024, cNG);
  // Wq [128][1024] -> WQT [1024][128] fp32
  k_transpose<<<dim3((1024 / 64) * (128 / 64)), dim3(256), 0, stream>>>(
      a.Wq, ws + WS_WQT, 128, 1024, cAD);
  // Wm [128][512] -> WMTR [512][128] fp32
  k_transpose<<<dim3((512 / 64) * (128 / 64)), dim3(256), 0, stream>>>(
      a.Wm, ws + WS_WMTR, 128, 512, cAD);

  k_prep_small<<<dim3((cKM * cNMP + 255) / 256), dim3(256), 0, stream>>>(a);
  k_prenet1<<<dim3(8000), dim3(256), 0, stream>>>(a);
  k_prenet2<<<dim3(8000), dim3(256), 0, stream>>>(a);
  k_pm<<<dim3(4096), dim3(256), 0, stream>>>(a);
  k_init<<<dim3(1056), dim3(256), 0, stream>>>(a);

  void* params[] = { (void*)&a };
  hipError_t err = hipLaunchCooperativeKernel((const void*)k_loop, dim3(256), dim3(512),
                                              params, 0, stream);
  if (err != hipSuccess) {
    fprintf(stderr, "kernel_launch: cooperative launch failed: %s\n",
            hipGetErrorString(err));
  }
}

// Round 4
// 39096.237 us; speedup vs baseline: 1.5123x; 1.5123x over previous
//
#include <hip/hip_runtime.h>
#include <cstdio>

// ---------------- dims ----------------
static constexpr int cB = 32, cTENC = 256, cENCD = 512, cTDEC = 500, cMEL = 80,
    cNSTEP = 250, cPRE = 256, cAD = 128, cAR = 1024, cDR = 1024, cFLT = 32,
    cKSZ = 31, cPADC = 15, cNG = 4096;
static constexpr int cKA = cPRE + cENCD + cAR;   // 1792 : [x | ctx | h_a]
static constexpr int cKD = cAR + cENCD + cDR;    // 2560 : [h_a | ctx | dec_h]
static constexpr int cKM = cDR + cENCD;          // 1536 : [dec_h | ctx]
static constexpr int cNMP = 192;                 // padded 161 (160 mel + 1 stop)
static constexpr int cNSA = 14;                  // attn k-splits (span 128)
static constexpr int cNSD = 16;                  // dec  k-splits (span 160)

typedef unsigned short ushortT;
typedef unsigned int uintT;
typedef unsigned long long ullT;

// ---------------- output layout (floats) ----------------
static constexpr size_t MEL_OFF = 0;
static constexpr size_t STOP_OFF = (size_t)cB * cTDEC * cMEL;      // 1,280,000
static constexpr size_t ATT_OFF = STOP_OFF + (size_t)cB * cTDEC;   // 1,296,000

// ---------------- workspace layout (float units) ----------------
static constexpr size_t WS_WATB = 0;                                   // us[1792][4096]
static constexpr size_t WS_WDTB = WS_WATB + (size_t)cKA * cNG / 2;     // us[2560][4096]
static constexpr size_t WS_WMT  = WS_WDTB + (size_t)cKD * cNG / 2;     // f[1536][192]
static constexpr size_t WS_WQT  = WS_WMT  + (size_t)cKM * cNMP;        // f[1024][128]
static constexpr size_t WS_WMTR = WS_WQT  + (size_t)cAR * cAD;         // f[512][128]
static constexpr size_t WS_PM   = WS_WMTR + (size_t)cENCD * cAD;       // f[32][256][128]
static constexpr size_t WS_XPRE = WS_PM   + (size_t)cB * cTENC * cAD;  // f[250][256][32]
static constexpr size_t WS_XA   = WS_XPRE + (size_t)cNSTEP * cPRE * cB;// f[2][1792][32]
static constexpr size_t WS_XD   = WS_XA   + (size_t)2 * cKA * cB;      // f[2560][32]
static constexpr size_t WS_CA   = WS_XD   + (size_t)cKD * cB;          // f[32][1024]
static constexpr size_t WS_CD   = WS_CA   + (size_t)cB * cAR;          // f[32][1024]
static constexpr size_t WS_CUM  = WS_CD   + (size_t)cB * cDR;          // f[32][256]
static constexpr size_t WS_CTR  = WS_CUM  + (size_t)cB * cTENC;        // u32[16]
static constexpr size_t WS_GA   = WS_CTR  + 16;                        // f[32][14][4096]
static constexpr size_t WS_GD   = WS_GA   + (size_t)cB * cNSA * cNG;   // f[32][16][4096]
static constexpr size_t WS_PROJ = WS_GD   + (size_t)cB * cNSD * cNG;   // f[250][1536][32]
static constexpr size_t WS_TOTAL = WS_PROJ + (size_t)cNSTEP * cKM * cB;
// X1 (prenet intermediate) aliases GA/GD region: used only pre-loop.
static constexpr size_t WS_X1   = WS_GA;                               // f[250][32][256]

struct Args {
  const float *enc, *inputs;
  const int *mlen;
  const float *W1, *b1, *W2, *b2, *Wm;
  const float *Wih_a, *Whh_a, *bih_a, *bhh_a;
  const float *Wq, *conv_w, *conv_b, *WL, *v;
  const float *Wih_d, *Whh_d, *bih_d, *bhh_d;
  const float *Wmel, *bmel, *Wstop, *bstop;
  float *out;
  float *ws;
};

union SharedU {
  float xs[(160 + 8) * 32];              // gemv x-slice stage (+PF over-read pad)
  struct {
    float h[cAR];
    float pq[cAD];
    float cumext[cTENC + 2 * cPADC];
    float eparts[2][cTENC];
    float e[cTENC];
    float sred[16];
    float loc[cFLT * 257];
    float wl[cAD * 33];
    float cw[cFLT * cKSZ];
    float vv[cAD];
  } attn;                                // ~63 KB
  float melred[cB][164];
};

// ---------- device-coherent (agent-scope, L2-non-dirtying) access ----------
__device__ __forceinline__ float ld_sc(const float* p) {
  return __hip_atomic_load(p, __ATOMIC_RELAXED, __HIP_MEMORY_SCOPE_AGENT);
}
__device__ __forceinline__ void st_sc(float* p, float v) {
  __hip_atomic_store(p, v, __ATOMIC_RELAXED, __HIP_MEMORY_SCOPE_AGENT);
}
__device__ __forceinline__ float2 ld_sc2(const float2* p) {
  ullT u = __hip_atomic_load((const ullT*)p, __ATOMIC_RELAXED, __HIP_MEMORY_SCOPE_AGENT);
  float2 r;
  r.x = __uint_as_float((uintT)u);
  r.y = __uint_as_float((uintT)(u >> 32));
  return r;
}
__device__ __forceinline__ void st_sc2(float2* p, float x, float y) {
  ullT u = (ullT)__float_as_uint(x) | ((ullT)__float_as_uint(y) << 32);
  __hip_atomic_store((ullT*)p, u, __ATOMIC_RELAXED, __HIP_MEMORY_SCOPE_AGENT);
}

// Monotonic grid barrier: no cache maintenance (all cross-WG data goes via sc).
// __syncthreads drains each thread's outstanding stores before the arrival add.
__device__ __forceinline__ void gbar(uintT* ctr, uintT target) {
  __syncthreads();
  if (threadIdx.x == 0) {
    __hip_atomic_fetch_add(ctr, 1u, __ATOMIC_RELAXED, __HIP_MEMORY_SCOPE_AGENT);
    while (__hip_atomic_load(ctr, __ATOMIC_RELAXED, __HIP_MEMORY_SCOPE_AGENT) < target) {
      __builtin_amdgcn_s_sleep(4);
    }
  }
  __syncthreads();
}

__device__ __forceinline__ float sigm_f(float x) { return 1.f / (1.f + __expf(-x)); }
__device__ __forceinline__ float tanh_f(float x) {
  float e = __expf(2.f * x);
  return 1.f - 2.f / (e + 1.f);
}

// Batch-32 GEMV partial, bf16 weights (plain cached; L2-resident across steps),
// x via sc loads staged to LDS, partials out via sc stores.
template <int KSPAN, int NS>
static __device__ void gemv_bf16(const ushortT* __restrict__ WT,
                                 const float* __restrict__ xT,
                                 float* __restrict__ part,
                                 int cb, int k0, int slot, float* __restrict__ xs) {
  const int tid = threadIdx.x;
  {
    const float2* src = (const float2*)(xT + (size_t)k0 * cB);
    float2* dst = (float2*)xs;
    for (int i = tid; i < KSPAN * 16; i += 512) dst[i] = ld_sc2(src + i);
  }
  __syncthreads();
  const int cq = tid & 63, bq = tid >> 6;           // 64 col-octets x 8 batch-quads
  const int col0 = cb * 512 + cq * 8;
  const ushortT* wp = WT + (size_t)k0 * cNG + col0;
  const float4* xp = (const float4*)xs + bq;        // stride 8 float4 per k
  float acc[8][4];
#pragma unroll
  for (int c = 0; c < 8; ++c)
#pragma unroll
    for (int j = 0; j < 4; ++j) acc[c][j] = 0.f;

  constexpr int PF = 8;                             // prefetch depth
  uint4 wbuf[PF];
  float4 xbuf[PF];
#pragma unroll
  for (int i = 0; i < PF; ++i) {
    wbuf[i] = *(const uint4*)(wp + (size_t)i * cNG);
    xbuf[i] = xp[(size_t)i * 8];
  }
  for (int kb = 0; kb < KSPAN; kb += PF) {
#pragma unroll
    for (int i = 0; i < PF; ++i) {
      const uint4 w = wbuf[i];
      const float4 x4 = xbuf[i];
      const size_t kn = (size_t)(kb + i + PF);
      wbuf[i] = *(const uint4*)(wp + kn * cNG);     // over-read past slice is benign
      xbuf[i] = xp[kn * 8];                         // LDS pad covers over-read
      float wf[8];
      wf[0] = __uint_as_float(w.x << 16);
      wf[1] = __uint_as_float(w.x & 0xFFFF0000u);
      wf[2] = __uint_as_float(w.y << 16);
      wf[3] = __uint_as_float(w.y & 0xFFFF0000u);
      wf[4] = __uint_as_float(w.z << 16);
      wf[5] = __uint_as_float(w.z & 0xFFFF0000u);
      wf[6] = __uint_as_float(w.w << 16);
      wf[7] = __uint_as_float(w.w & 0xFFFF0000u);
      const float xv[4] = {x4.x, x4.y, x4.z, x4.w};
#pragma unroll
      for (int c = 0; c < 8; ++c)
#pragma unroll
        for (int j = 0; j < 4; ++j) acc[c][j] = fmaf(wf[c], xv[j], acc[c][j]);
    }
  }
  const int b0 = bq * 4;
#pragma unroll
  for (int j = 0; j < 4; ++j) {
    float2* dst = (float2*)&part[(((size_t)(b0 + j)) * NS + slot) * cNG + col0];
    st_sc2(dst + 0, acc[0][j], acc[1][j]);
    st_sc2(dst + 1, acc[2][j], acc[3][j]);
    st_sc2(dst + 2, acc[4][j], acc[5][j]);
    st_sc2(dst + 3, acc[6][j], acc[7][j]);
  }
  __syncthreads();
}

// Decoder LSTM cell for batch b, step s.
static __device__ void dec_cell(const Args& a, float* ws, int b, int s) {
  const int tid = threadIdx.x;
  const float* gd = ws + WS_GD + (size_t)b * cNSD * cNG;
  for (int h = tid; h < cDR; h += 512) {
    float g4[4];
#pragma unroll
    for (int gi = 0; gi < 4; ++gi) {
      const int n = gi * cDR + h;
      float sm = a.bih_d[n] + a.bhh_d[n];
#pragma unroll
      for (int p = 0; p < cNSD; ++p) sm += ld_sc(gd + (size_t)p * cNG + n);
      g4[gi] = sm;
    }
    const float co = ld_sc(ws + WS_CD + (size_t)b * cDR + h);
    const float cn = sigm_f(g4[1]) * co + sigm_f(g4[0]) * tanh_f(g4[2]);
    const float hn = sigm_f(g4[3]) * tanh_f(cn);
    st_sc(ws + WS_CD + (size_t)b * cDR + h, cn);
    st_sc(ws + WS_XD + (size_t)(cAR + cENCD + h) * cB + b, hn);
    st_sc(ws + WS_PROJ + ((size_t)s * cKM + h) * cB + b, hn);
  }
}

// Attention workgroup for batch b at step t.
static __device__ void attn_wg(const Args& a, float* ws, int b, int t,
                               float* __restrict__ xa2, SharedU& sh) {
  const int tid = threadIdx.x;
  const float* ga = ws + WS_GA + (size_t)b * cNSA * cNG;
  // 1. reduce ga partials + attn LSTM cell
  for (int h = tid; h < cAR; h += 512) {
    float g4[4];
#pragma unroll
    for (int gi = 0; gi < 4; ++gi) {
      const int n = gi * cAR + h;
      float s = a.bih_a[n] + a.bhh_a[n];
#pragma unroll
      for (int p = 0; p < cNSA; ++p) s += ld_sc(ga + (size_t)p * cNG + n);
      g4[gi] = s;
    }
    const float co = ld_sc(ws + WS_CA + (size_t)b * cAR + h);
    const float cn = sigm_f(g4[1]) * co + sigm_f(g4[0]) * tanh_f(g4[2]);
    const float hn = sigm_f(g4[3]) * tanh_f(cn);
    st_sc(ws + WS_CA + (size_t)b * cAR + h, cn);
    sh.attn.h[h] = hn;
    st_sc(xa2 + (size_t)(cPRE + cENCD + h) * cB + b, hn);
    st_sc(ws + WS_XD + (size_t)h * cB + b, hn);
  }
  __syncthreads();
  // 2. pq partials + small LDS loads
  {
    const int d = tid & 127, kc = tid >> 7;
    float acc = 0.f;
    const float* wq = ws + WS_WQT;
    const int k0 = kc * 256;
    for (int k = k0; k < k0 + 256; ++k) acc = fmaf(sh.attn.h[k], wq[(size_t)k * cAD + d], acc);
    sh.attn.loc[kc * 128 + d] = acc;
  }
  for (int i = tid; i < cAD * 33; i += 512) {
    const int dd = i / 33, f = i - dd * 33;
    sh.attn.wl[i] = (f < cFLT) ? a.WL[dd * cFLT + f] : 0.f;
  }
  for (int i = tid; i < cFLT * cKSZ; i += 512) sh.attn.cw[i] = a.conv_w[i];
  if (tid < cAD) sh.attn.vv[tid] = a.v[tid];
  if (tid < cTENC) sh.attn.cumext[cPADC + tid] = ld_sc(ws + WS_CUM + (size_t)b * cTENC + tid);
  if (tid < 2 * cPADC) sh.attn.cumext[tid < cPADC ? tid : cTENC + tid] = 0.f;
  __syncthreads();
  if (tid < cAD)
    sh.attn.pq[tid] = sh.attn.loc[tid] + sh.attn.loc[128 + tid] +
                      sh.attn.loc[256 + tid] + sh.attn.loc[384 + tid];
  __syncthreads();
  // 3. conv31 over cum
  for (int i = tid; i < cFLT * cTENC; i += 512) {
    const int f = i >> 8, te = i & 255;
    float s = a.conv_b[f];
#pragma unroll
    for (int j = 0; j < cKSZ; ++j) s = fmaf(sh.attn.cumext[te + j], sh.attn.cw[f * cKSZ + j], s);
    sh.attn.loc[f * 257 + te] = s;
  }
  __syncthreads();
  // 4. energies
  {
    const int d = tid & 127, tq = tid >> 7, wv = tid >> 6;
    float wlr[cFLT];
#pragma unroll
    for (int f = 0; f < cFLT; ++f) wlr[f] = sh.attn.wl[d * 33 + f];
    const float pqd = sh.attn.pq[d], vd = sh.attn.vv[d];
    const float* pmb = ws + WS_PM + (size_t)b * cTENC * cAD;
    for (int tt = 0; tt < cTENC / 4; ++tt) {
      const int te = tt * 4 + tq;
      float s = pqd + pmb[(size_t)te * cAD + d];
#pragma unroll
      for (int f = 0; f < cFLT; ++f) s = fmaf(sh.attn.loc[f * 257 + te], wlr[f], s);
      float p = tanh_f(s) * vd;
#pragma unroll
      for (int off = 32; off > 0; off >>= 1) p += __shfl_xor(p, off, 64);
      if ((tid & 63) == 0) sh.attn.eparts[wv & 1][te] = p;
    }
  }
  __syncthreads();
  // 5. mask + softmax over 256
  const int mlen = a.mlen[b];
  if (tid < cTENC) {
    float ev = sh.attn.eparts[0][tid] + sh.attn.eparts[1][tid];
    if (tid >= mlen) ev = -1e9f;
    sh.attn.e[tid] = ev;
  }
  __syncthreads();
  const int wv = tid >> 6;
  {
    float xv = sh.attn.e[tid & 255];
#pragma unroll
    for (int off = 32; off > 0; off >>= 1) xv = fmaxf(xv, __shfl_xor(xv, off, 64));
    if ((tid & 63) == 0) sh.attn.sred[wv] = xv;
  }
  __syncthreads();
  float m = sh.attn.sred[0];
#pragma unroll
  for (int i = 1; i < 8; ++i) m = fmaxf(m, sh.attn.sred[i]);
  const float pex = (tid < cTENC) ? __expf(sh.attn.e[tid] - m) : 0.f;
  {
    float sv = pex;
#pragma unroll
    for (int off = 32; off > 0; off >>= 1) sv += __shfl_xor(sv, off, 64);
    if ((tid & 63) == 0) sh.attn.sred[8 + wv] = sv;
  }
  __syncthreads();
  float ssum = 0.f;
#pragma unroll
  for (int i = 0; i < 8; ++i) ssum += sh.attn.sred[8 + i];
  const float rs = 1.f / ssum;
  if (tid < cTENC) {
    const float al = pex * rs;
    sh.attn.e[tid] = al;
    a.out[ATT_OFF + ((size_t)b * cNSTEP + t) * cTENC + tid] = al;
    st_sc(ws + WS_CUM + (size_t)b * cTENC + tid, sh.attn.cumext[cPADC + tid] + al);
  }
  __syncthreads();
  // 6. ctx = align @ encoder_outputs[b]
  {
    const int k = tid;   // 512 = ENCD
    float acc = 0.f;
    const float* encb = a.enc + (size_t)b * cTENC * cENCD + k;
    for (int te = 0; te < cTENC; ++te) acc = fmaf(sh.attn.e[te], encb[(size_t)te * cENCD], acc);
    st_sc(xa2 + (size_t)(cPRE + k) * cB + b, acc);
    st_sc(ws + WS_XD + (size_t)(cAR + k) * cB + b, acc);
    st_sc(ws + WS_PROJ + ((size_t)t * cKM + cDR + k) * cB + b, acc);
  }
}

// Post-loop batched mel/stop projection over all steps.
static __device__ void mel_proj(const Args& a, float* ws, SharedU& sh) {
  const int tid = threadIdx.x;
  const int c = tid & 255, sub = tid >> 8;   // two 768-row K halves
  for (int t = blockIdx.x; t < cNSTEP; t += gridDim.x) {
    float acc[cB];
#pragma unroll
    for (int b = 0; b < cB; ++b) acc[b] = 0.f;
    if (c < 161) {
      const float* wmt = ws + WS_WMT;
      const float* xr0 = ws + WS_PROJ + (size_t)t * cKM * cB;
      const int k0 = sub * 768;
      for (int k = k0; k < k0 + 768; ++k) {
        const float w = wmt[(size_t)k * cNMP + c];
        const float* xr = xr0 + (size_t)k * cB;
#pragma unroll
        for (int b = 0; b < cB; ++b) acc[b] = fmaf(w, ld_sc(xr + b), acc[b]);
      }
    }
    __syncthreads();
    if (sub == 1 && c < 161) {
#pragma unroll
      for (int b = 0; b < cB; ++b) sh.melred[b][c] = acc[b];
    }
    __syncthreads();
    if (sub == 0 && c < 161) {
      if (c < 160) {
        const int fr = c / 80, mm = c % 80;
        const float bm = a.bmel[c];
#pragma unroll
        for (int b = 0; b < cB; ++b) {
          const float val = acc[b] + sh.melred[b][c] + bm;
          a.out[MEL_OFF + ((size_t)b * cTDEC + (2 * t + fr)) * cMEL + mm] = val;
        }
      } else {
        const float bs = a.bstop[0];
#pragma unroll
        for (int b = 0; b < cB; ++b) {
          const float sp = sigm_f(acc[b] + sh.melred[b][c] + bs);
          a.out[STOP_OFF + (size_t)b * cTDEC + 2 * t] = sp;
          a.out[STOP_OFF + (size_t)b * cTDEC + 2 * t + 1] = sp;
        }
      }
    }
    __syncthreads();
  }
}

// ---------------- setup kernels ----------------
__device__ __forceinline__ ushortT f2b(float f) {
  const uintT u = __float_as_uint(f);
  return (ushortT)((u + 0x7FFFu + ((u >> 16) & 1u)) >> 16);   // RNE
}

__global__ void k_transpose(const float* __restrict__ src, float* __restrict__ dst,
                            int N, int K, int dpitch) {
  __shared__ float tile[64][65];
  const int tkn = K >> 6;
  const int tk = blockIdx.x % tkn, tn = blockIdx.x / tkn;
  const int c = threadIdx.x & 63, r4 = threadIdx.x >> 6;
  const int n0 = tn << 6, k0 = tk << 6;
#pragma unroll
  for (int rr = 0; rr < 16; ++rr) {
    const int r = r4 * 16 + rr;
    tile[r][c] = src[(size_t)(n0 + r) * K + k0 + c];
  }
  __syncthreads();
#pragma unroll
  for (int rr = 0; rr < 16; ++rr) {
    const int r = r4 * 16 + rr;
    dst[(size_t)(k0 + r) * dpitch + n0 + c] = tile[c][r];
  }
}

__global__ void k_transpose_b16(const float* __restrict__ src, ushortT* __restrict__ dst,
                                int N, int K, int dpitch) {
  __shared__ float tile[64][65];
  const int tkn = K >> 6;
  const int tk = blockIdx.x % tkn, tn = blockIdx.x / tkn;
  const int c = threadIdx.x & 63, r4 = threadIdx.x >> 6;
  const int n0 = tn << 6, k0 = tk << 6;
#pragma unroll
  for (int rr = 0; rr < 16; ++rr) {
    const int r = r4 * 16 + rr;
    tile[r][c] = src[(size_t)(n0 + r) * K + k0 + c];
  }
  __syncthreads();
#pragma unroll
  for (int rr = 0; rr < 16; ++rr) {
    const int r = r4 * 16 + rr;
    dst[(size_t)(k0 + r) * dpitch + n0 + c] = f2b(tile[c][r]);
  }
}

__global__ void k_prep_small(Args a) {
  const size_t i = (size_t)blockIdx.x * blockDim.x + threadIdx.x;
  if (i < 16) ((uintT*)(a.ws + WS_CTR))[i] = 0u;   // barrier counters
  if (i >= (size_t)cKM * cNMP) return;
  const int k = (int)(i / cNMP), c = (int)(i % cNMP);
  a.ws[WS_WMT + i] = (c < 160) ? a.Wmel[(size_t)c * cKM + k]
                               : (c == 160 ? a.Wstop[k] : 0.f);
}

__global__ void k_prenet1(Args a) {
  const size_t i = (size_t)blockIdx.x * blockDim.x + threadIdx.x;
  if (i >= (size_t)cNSTEP * cB * cPRE) return;
  const int j = i & 255, b = (i >> 8) & 31, n = (int)(i >> 13);
  float acc = a.b1[j];
  if (n > 0) {
    const float* fr = a.inputs + ((size_t)b * cTDEC + (2 * n - 1)) * cMEL;
    for (int k = 0; k < cMEL; ++k) acc = fmaf(fr[k], a.W1[j * cMEL + k], acc);
  }
  a.ws[WS_X1 + i] = fmaxf(acc, 0.f);
}

__global__ void k_prenet2(Args a) {
  const size_t i = (size_t)blockIdx.x * blockDim.x + threadIdx.x;
  if (i >= (size_t)cNSTEP * cPRE * cB) return;
  const int b = i & 31, j = (i >> 5) & 255, n = (int)(i >> 13);
  float acc = a.b2[j];
  const float* x1 = a.ws + WS_X1 + ((size_t)n * cB + b) * cPRE;
  for (int k = 0; k < cPRE; ++k) acc = fmaf(x1[k], a.W2[j * cPRE + k], acc);
  a.ws[WS_XPRE + i] = fmaxf(acc, 0.f);   // layout [n][j][b]
}

__global__ void k_pm(Args a) {
  const size_t i = (size_t)blockIdx.x * blockDim.x + threadIdx.x;
  if (i >= (size_t)cB * cTENC * cAD) return;
  const int d = i & 127, tt = (i >> 7) & 255, b = (int)(i >> 15);
  float acc = 0.f;
  const float* er = a.enc + ((size_t)b * cTENC + tt) * cENCD;
  const float* wt = a.ws + WS_WMTR;
  for (int k = 0; k < cENCD; ++k) acc = fmaf(er[k], wt[(size_t)k * cAD + d], acc);
  a.ws[WS_PM + i] = acc;
}

// ---------------- persistent cooperative loop ----------------
// PhaseA(t) = attn-gates GEMV(t) || dec-gates GEMV(t-1)
// PhaseB(t) = attention(t)+ctx(t) || dec_cell(t-1) || x-copy(t+1)
// Barriers: monotonic atomic counter; cross-WG data via agent-scope sc ops.
__global__ void __launch_bounds__(512, 1) k_loop(Args a) {
  __shared__ SharedU sh;
  float* ws = a.ws;
  uintT* ctr = (uintT*)(ws + WS_CTR);
  const ushortT* watb = (const ushortT*)(ws + WS_WATB);
  const ushortT* wdtb = (const ushortT*)(ws + WS_WDTB);
  const int wg = blockIdx.x;
  const int tid = threadIdx.x;
  uintT ph = 0;

  // ---- in-kernel init (owner WGs; all via sc so any XCD mapping is safe) ----
  float* xa0 = ws + WS_XA;
  if (wg < 32) {
    const int b = wg;
    for (int i = tid; i < cTENC; i += 512) st_sc(ws + WS_CUM + (size_t)b * cTENC + i, 0.f);
    for (int i = tid; i < cAR; i += 512) st_sc(ws + WS_CA + (size_t)b * cAR + i, 0.f);
  } else if (wg < 64) {
    const int b = wg - 32;
    for (int i = tid; i < cDR; i += 512) st_sc(ws + WS_CD + (size_t)b * cDR + i, 0.f);
  } else if (wg < 80) {
    const int i = (wg - 64) * 512 + tid;               // 8192 = PRE*B
    st_sc(xa0 + i, ld_sc(ws + WS_XPRE + i));
  } else if (wg < 176) {
    const int i = (wg - 80) * 512 + tid;               // 49152 = (ENCD+AR)*B
    st_sc(xa0 + (size_t)cPRE * cB + i, 0.f);
  } else if (wg < 240) {
    const int i = (wg - 176) * 512 + tid;              // 32768 = DR*B
    st_sc(ws + WS_XD + (size_t)(cAR + cENCD) * cB + i, 0.f);
  }
  ++ph; gbar(ctr, ph * 256u);

  for (int t = 0; t <= cNSTEP; ++t) {
    const float* xa = ws + WS_XA + (size_t)(t & 1) * cKA * cB;
    float* xa2 = ws + WS_XA + (size_t)((t + 1) & 1) * cKA * cB;
    // ---- Phase A ----
    if (wg < 112) {
      if (t < cNSTEP) {
        const int s = wg >> 3, cb = wg & 7;
        gemv_bf16<128, cNSA>(watb, xa, ws + WS_GA, cb, s * 128, s, sh.xs);
      }
    } else if (wg < 240) {
      if (t >= 1) {
        const int i = wg - 112, s = i >> 3, cb = i & 7;
        gemv_bf16<160, cNSD>(wdtb, ws + WS_XD, ws + WS_GD, cb, s * 160, s, sh.xs);
      }
    }
    ++ph; gbar(ctr, ph * 256u);
    // ---- Phase B ----
    if (wg < 32) {
      if (t < cNSTEP) attn_wg(a, ws, wg, t, xa2, sh);
    } else if (wg < 64) {
      if (t >= 1) dec_cell(a, ws, wg - 32, t - 1);
    } else if (wg < 80) {
      if (t + 1 < cNSTEP) {
        const int i = (wg - 64) * 512 + tid;   // 16*512 = 8192 = PRE*B
        st_sc(xa2 + i, ld_sc(ws + WS_XPRE + (size_t)(t + 1) * cPRE * cB + i));
      }
    }
    ++ph; gbar(ctr, ph * 256u);
  }
  mel_proj(a, ws, sh);
}

// ---------------- host ----------------
extern "C" void kernel_launch(void* const* d_in, const int* in_sizes, int n_in,
                              void* d_out, int out_size, void* d_ws, size_t ws_size,
                              hipStream_t stream) {
  (void)in_sizes; (void)n_in; (void)out_size;
  Args a;
  a.enc = (const float*)d_in[0];
  a.inputs = (const float*)d_in[1];
  a.mlen = (const int*)d_in[2];
  a.W1 = (const float*)d_in[3];  a.b1 = (const float*)d_in[4];
  a.W2 = (const float*)d_in[5];  a.b2 = (const float*)d_in[6];
  a.Wm = (const float*)d_in[7];
  a.Wih_a = (const float*)d_in[8];  a.Whh_a = (const float*)d_in[9];
  a.bih_a = (const float*)d_in[10]; a.bhh_a = (const float*)d_in[11];
  a.Wq = (const float*)d_in[12];
  a.conv_w = (const float*)d_in[13]; a.conv_b = (const float*)d_in[14];
  a.WL = (const float*)d_in[15];     a.v = (const float*)d_in[16];
  a.Wih_d = (const float*)d_in[17];  a.Whh_d = (const float*)d_in[18];
  a.bih_d = (const float*)d_in[19];  a.bhh_d = (const float*)d_in[20];
  a.Wmel = (const float*)d_in[21];   a.bmel = (const float*)d_in[22];
  a.Wstop = (const float*)d_in[23];  a.bstop = (const float*)d_in[24];
  a.out = (float*)d_out;
  a.ws = (float*)d_ws;

  if (ws_size < WS_TOTAL * sizeof(float)) {
    fprintf(stderr, "kernel_launch: ws too small: need %zu bytes, have %zu\n",
            WS_TOTAL * sizeof(float), ws_size);
    return;
  }

  float* ws = a.ws;
  ushortT* watb = (ushortT*)(ws + WS_WATB);
  ushortT* wdtb = (ushortT*)(ws + WS_WDTB);
  k_transpose_b16<<<dim3((768 / 64) * (4096 / 64)), dim3(256), 0, stream>>>(
      a.Wih_a, watb, 4096, 768, cNG);
  k_transpose_b16<<<dim3((1024 / 64) * (4096 / 64)), dim3(256), 0, stream>>>(
      a.Whh_a, watb + (size_t)768 * cNG, 4096, 1024, cNG);
  k_transpose_b16<<<dim3((1536 / 64) * (4096 / 64)), dim3(256), 0, stream>>>(
      a.Wih_d, wdtb, 4096, 1536, cNG);
  k_transpose_b16<<<dim3((1024 / 64) * (4096 / 64)), dim3(256), 0, stream>>>(
      a.Whh_d, wdtb + (size_t)1536 * cNG, 4096, 1024, cNG);
  k_transpose<<<dim3((1024 / 64) * (128 / 64)), dim3(256), 0, stream>>>(
      a.Wq, ws + WS_WQT, 128, 1024, cAD);
  k_transpose<<<dim3((512 / 64) * (128 / 64)), dim3(256), 0, stream>>>(
      a.Wm, ws + WS_WMTR, 128, 512, cAD);

  k_prep_small<<<dim3((cKM * cNMP + 255) / 256), dim3(256), 0, stream>>>(a);
  k_prenet1<<<dim3(8000), dim3(256), 0, stream>>>(a);
  k_prenet2<<<dim3(8000), dim3(256), 0, stream>>>(a);
  k_pm<<<dim3(4096), dim3(256), 0, stream>>>(a);

  void* params[] = { (void*)&a };
  hipError_t err = hipLaunchCooperativeKernel((const void*)k_loop, dim3(256), dim3(512),
                                              params, 0, stream);
  if (err != hipSuccess) {
    fprintf(stderr, "kernel_launch: cooperative launch failed: %s\n",
            hipGetErrorString(err));
  }
}